// Round 1
// 592.511 us; speedup vs baseline: 1.1866x; 1.1866x over previous
//
#include <hip/hip_runtime.h>

typedef unsigned short u16;
typedef _Float16 f16;
typedef _Float16 f16x4 __attribute__((ext_vector_type(4)));
typedef _Float16 f16x8 __attribute__((ext_vector_type(8)));
typedef float f32x4 __attribute__((ext_vector_type(4)));

#define GLL16(gptr, lptr)                                                        \
  __builtin_amdgcn_global_load_lds(                                              \
      (const __attribute__((address_space(1))) void*)(gptr),                     \
      (__attribute__((address_space(3))) void*)(lptr), 16, 0, 0)

// ---- cast all six fp32 inputs to fp16 in ONE dispatch (float4 units) ------
__global__ void cast_all_k(const float* __restrict__ h, const float* __restrict__ t,
                           const float* __restrict__ wq, const float* __restrict__ wk,
                           const float* __restrict__ wv, const float* __restrict__ wo,
                           f16* __restrict__ Xcat, f16* __restrict__ Wqb,
                           f16* __restrict__ Wkvb, f16* __restrict__ Wob) {
  long i = (long)blockIdx.x * 256 + threadIdx.x;
  const float* s; f16* d; long off;
  if (i < 2097152)        { s = h;  d = Xcat;            off = i; }
  else if (i < 4194304)   { s = t;  d = Xcat + 8388608;  off = i - 2097152; }
  else if (i < 8388608)   { s = wq; d = Wqb;             off = i - 4194304; }
  else if (i < 9437184)   { s = wk; d = Wkvb;            off = i - 8388608; }
  else if (i < 10485760)  { s = wv; d = Wkvb + 4194304;  off = i - 9437184; }
  else                    { s = wo; d = Wob;             off = i - 10485760; }
  float4 v = *(const float4*)(s + off * 4);
  f16x4 o;
  o.x = (f16)v.x; o.y = (f16)v.y; o.z = (f16)v.z; o.w = (f16)v.w;
  *(f16x4*)(d + off * 4) = o;
}

// ===========================================================================
// 256x256 8-phase GEMM-BT (BK=64), plain-HIP port of the verified m201
// template: T1 XCD swizzle + T2 LDS XOR swizzle + T3/T4 counted vmcnt +
// T5 setprio.  512 threads = 8 waves, 4M x 2N geometry: wave owns 64 rows x
// 128 cols so a full head's d-range is in-register -> rope pairs (d, d+64)
// are acc[mi][ni] / acc[mi][ni+4] (ports the verified epilogues unchanged).
//
// LDS (f16 units): A dbuf [0,16384)+[16384,32768), B dbuf [32768..65536).
// Tile = 256 rows x 64 f16 (128B rows); half-tile = 128 rows = 8192 f16.
// Swizzle: 16B-chunk' = chunk ^ (row&7); staged via inverse-swizzled GLOBAL
// source (global_load_lds dest must stay linear), read with the same XOR.
//
// Counted-vmcnt schedule (2 loads per STAGE, safety-verified):
//   per tile t (buf c=t&1):  p1: stage A0(t+1)->c^1   (A0(t-1) consumed @ (t-1).p3)
//                            p2: stage A1(t+1)->c^1
//                            p3: stage B0(t+2)->c     (B0(t) consumed @ t.p2)
//                            p4: stage B1(t+2)->c, then s_waitcnt vmcnt(4)
//   vmcnt(4) leaves exactly B0/B1(t+2) in flight and guarantees all of tile
//   t+1 (A1 issued @ t.p2 is the newest needed) has landed. Never drains to 0
//   until the last two tiles.
// MODE 0: fused QKV projection (rope + V^T epilogues).  MODE 1: O-proj
// split-K=2 fp32 partials.
// ===========================================================================
template <int MODE>
__global__ __launch_bounds__(512, 2) void gemm8k(
    const f16* __restrict__ Xcat, const f16* __restrict__ Wqb,
    const f16* __restrict__ Wkvb, const float* __restrict__ cosT,
    const float* __restrict__ sinT, f16* __restrict__ Qb, f16* __restrict__ Kb,
    f16* __restrict__ Vt, const f16* __restrict__ Ao,
    const f16* __restrict__ Wob, float* __restrict__ Cp, float qscale) {
  __shared__ __align__(16) f16 lds[65536];  // 128 KiB
  const int tid = threadIdx.x;
  const int w = tid >> 6, lane = tid & 63;
  const int quad = lane >> 4, l16 = lane & 15;
  const int wm = w >> 1, wn = w & 1;

  // T1: XCD-aware block swizzle (nwg=256, 256%8==0 -> bijective)
  int b = (int)blockIdx.x;
  int l = ((b & 7) << 5) | (b >> 3);

  const f16 *A, *B;
  long tM, tN;
  int NT, kbeg;
  bool isQ = false, isV = false;
  float* Cz = nullptr;
  if (MODE == 0) {
    kbeg = 0; NT = 64;
    if (l < 128) {  // Q: M=2048 (8 tiles) x N=4096 (16 tiles)
      A = Xcat; B = Wqb; tM = (long)(l >> 4) * 256; tN = (long)(l & 15) * 256;
      isQ = true;
    } else {        // KV: M=4096 (16) x N=2048 (8); cols>=1024 are V
      int l2 = l - 128;
      A = Xcat; B = Wkvb; tM = (long)(l2 >> 3) * 256; tN = (long)(l2 & 7) * 256;
      isV = (tN >= 1024);
    }
  } else {          // O-proj: M=2048 (8) x N=4096 (16), split-K z in {0,1}
    int z = l >> 7, r0 = l & 127;
    A = Ao; B = Wob; tM = (long)(r0 >> 4) * 256; tN = (long)(r0 & 15) * 256;
    kbeg = z * 2048; NT = 32; Cz = Cp + (long)z * 8388608;
  }

  // ---- staging addresses: wave w covers rows 16w..16w+15 of a half-tile ---
  // lane l -> row 16w + (l>>3) (+8 for 2nd GLL), LDS chunk l&7 holds global
  // chunk (l&7)^(l>>3)  (row&7 == l>>3 since bases are 8-aligned).
  const int sr8 = lane >> 3;
  const int cg = (lane & 7) ^ sr8;
  const f16* Ag = A + (tM + 16 * w + sr8) * 4096 + kbeg + cg * 8;
  const f16* Bg = B + (tN + 16 * w + sr8) * 4096 + kbeg + cg * 8;
  const int ldsw = w * 1024;  // wave segment base inside a half-tile (f16)

#define STAGE_A(hf, t, c)                                                      \
  do {                                                                         \
    const f16* g_ = Ag + (long)(t) * 64 + (long)(hf) * (128 * 4096);           \
    f16* d_ = &lds[(c) * 16384 + (hf) * 8192 + ldsw];                          \
    GLL16(g_, d_);                                                             \
    GLL16(g_ + 8 * 4096, d_ + 512);                                            \
  } while (0)
#define STAGE_B(hf, t, c)                                                      \
  do {                                                                         \
    const f16* g_ = Bg + (long)(t) * 64 + (long)(hf) * (128 * 4096);           \
    f16* d_ = &lds[32768 + (c) * 16384 + (hf) * 8192 + ldsw];                  \
    GLL16(g_, d_);                                                             \
    GLL16(g_ + 8 * 4096, d_ + 512);                                            \
  } while (0)

  // ---- fragment reads (T2 swizzled): row&7 == l16&7 for all frag rows -----
  const int rA = wm * 64 + l16;    // + mi*16
  const int rB = wn * 128 + l16;   // + ni*16
  const int sw = l16 & 7;
#define LDA(fr, mi, kk, c)                                                     \
  fr = *(const f16x8*)&lds[(c) * 16384 + (rA + (mi) * 16) * 64 +               \
                           (((kk) * 4 + quad) ^ sw) * 8]
#define LDB(fr, ni, kk, c)                                                     \
  fr = *(const f16x8*)&lds[32768 + (c) * 16384 + (rB + (ni) * 16) * 64 +       \
                           (((kk) * 4 + quad) ^ sw) * 8]

#define MFMA16 __builtin_amdgcn_mfma_f32_16x16x32_f16
#define BAR() __builtin_amdgcn_s_barrier()
#define WAITDS()                                                               \
  do {                                                                         \
    asm volatile("s_waitcnt lgkmcnt(0)" ::: "memory");                         \
    __builtin_amdgcn_sched_barrier(0);                                         \
  } while (0)

  f32x4 acc[4][8] = {};
  f16x8 af[2][2], bf0[4][2], bf1[4][2];

  // prologue: ages must mimic steady state (B(t) older than A(t))
  STAGE_B(0, 0, 0); STAGE_B(1, 0, 0); STAGE_A(0, 0, 0); STAGE_A(1, 0, 0);
  STAGE_B(0, 1, 1); STAGE_B(1, 1, 1);
  asm volatile("s_waitcnt vmcnt(4)" ::: "memory");  // tile0 landed; B(1) in flight
  BAR();

#define TILE_STEP(t, c)                                                        \
  do {                                                                         \
    /* ---- phase 1: acc[0..1][0..3] ---- */                                   \
    LDA(af[0][0], 0, 0, c); LDA(af[0][1], 0, 1, c);                            \
    LDA(af[1][0], 1, 0, c); LDA(af[1][1], 1, 1, c);                            \
    LDB(bf0[0][0], 0, 0, c); LDB(bf0[0][1], 0, 1, c);                          \
    LDB(bf0[1][0], 1, 0, c); LDB(bf0[1][1], 1, 1, c);                          \
    LDB(bf0[2][0], 2, 0, c); LDB(bf0[2][1], 2, 1, c);                          \
    LDB(bf0[3][0], 3, 0, c); LDB(bf0[3][1], 3, 1, c);                          \
    if ((t) + 1 < NT) STAGE_A(0, (t) + 1, (c) ^ 1);                            \
    BAR(); WAITDS();                                                           \
    __builtin_amdgcn_s_setprio(1);                                             \
    _Pragma("unroll") for (int mi = 0; mi < 2; ++mi)                           \
        _Pragma("unroll") for (int ni = 0; ni < 4; ++ni) {                     \
      acc[mi][ni] = MFMA16(af[mi][0], bf0[ni][0], acc[mi][ni], 0, 0, 0);       \
      acc[mi][ni] = MFMA16(af[mi][1], bf0[ni][1], acc[mi][ni], 0, 0, 0);       \
    }                                                                          \
    __builtin_amdgcn_s_setprio(0);                                             \
    BAR();                                                                     \
    /* ---- phase 2: acc[0..1][4..7] ---- */                                   \
    LDB(bf1[0][0], 4, 0, c); LDB(bf1[0][1], 4, 1, c);                          \
    LDB(bf1[1][0], 5, 0, c); LDB(bf1[1][1], 5, 1, c);                          \
    LDB(bf1[2][0], 6, 0, c); LDB(bf1[2][1], 6, 1, c);                          \
    LDB(bf1[3][0], 7, 0, c); LDB(bf1[3][1], 7, 1, c);                          \
    if ((t) + 1 < NT) STAGE_A(1, (t) + 1, (c) ^ 1);                            \
    BAR(); WAITDS();                                                           \
    __builtin_amdgcn_s_setprio(1);                                             \
    _Pragma("unroll") for (int mi = 0; mi < 2; ++mi)                           \
        _Pragma("unroll") for (int ni = 0; ni < 4; ++ni) {                     \
      acc[mi][4 + ni] =                                                        \
          MFMA16(af[mi][0], bf1[ni][0], acc[mi][4 + ni], 0, 0, 0);             \
      acc[mi][4 + ni] =                                                        \
          MFMA16(af[mi][1], bf1[ni][1], acc[mi][4 + ni], 0, 0, 0);             \
    }                                                                          \
    __builtin_amdgcn_s_setprio(0);                                             \
    BAR();                                                                     \
    /* ---- phase 3: acc[2..3][0..3] (af reloaded with mi 2..3) ---- */        \
    LDA(af[0][0], 2, 0, c); LDA(af[0][1], 2, 1, c);                            \
    LDA(af[1][0], 3, 0, c); LDA(af[1][1], 3, 1, c);                            \
    if ((t) + 2 < NT) STAGE_B(0, (t) + 2, c);                                  \
    BAR(); WAITDS();                                                           \
    __builtin_amdgcn_s_setprio(1);                                             \
    _Pragma("unroll") for (int mi = 0; mi < 2; ++mi)                           \
        _Pragma("unroll") for (int ni = 0; ni < 4; ++ni) {                     \
      acc[2 + mi][ni] = MFMA16(af[mi][0], bf0[ni][0], acc[2 + mi][ni], 0, 0, 0);\
      acc[2 + mi][ni] = MFMA16(af[mi][1], bf0[ni][1], acc[2 + mi][ni], 0, 0, 0);\
    }                                                                          \
    __builtin_amdgcn_s_setprio(0);                                             \
    BAR();                                                                     \
    /* ---- phase 4: acc[2..3][4..7], single counted vmcnt per K-tile ---- */  \
    if ((t) + 2 < NT) STAGE_B(1, (t) + 2, c);                                  \
    BAR();                                                                     \
    __builtin_amdgcn_s_setprio(1);                                             \
    _Pragma("unroll") for (int mi = 0; mi < 2; ++mi)                           \
        _Pragma("unroll") for (int ni = 0; ni < 4; ++ni) {                     \
      acc[2 + mi][4 + ni] =                                                    \
          MFMA16(af[mi][0], bf1[ni][0], acc[2 + mi][4 + ni], 0, 0, 0);         \
      acc[2 + mi][4 + ni] =                                                    \
          MFMA16(af[mi][1], bf1[ni][1], acc[2 + mi][4 + ni], 0, 0, 0);         \
    }                                                                          \
    __builtin_amdgcn_s_setprio(0);                                             \
    if ((t) + 2 < NT)                                                          \
      asm volatile("s_waitcnt vmcnt(4)" ::: "memory");                         \
    else                                                                       \
      asm volatile("s_waitcnt vmcnt(0)" ::: "memory");                         \
    BAR();                                                                     \
  } while (0)

  for (int t = 0; t < NT; t += 2) {
    TILE_STEP(t, 0);
    TILE_STEP(t + 1, 1);
  }

  // ------------------------------ epilogues --------------------------------
  if (MODE == 1) {
#pragma unroll
    for (int mi = 0; mi < 4; ++mi)
#pragma unroll
      for (int ni = 0; ni < 8; ++ni)
#pragma unroll
        for (int r = 0; r < 4; ++r) {
          long row = tM + wm * 64 + mi * 16 + quad * 4 + r;
          long col = tN + wn * 128 + ni * 16 + l16;
          Cz[row * 4096 + col] = acc[mi][ni][r];
        }
  } else if (isV) {
    // V: write V^T directly; lane has 4 consecutive keys per (mi,ni).
    const int kvh = (int)((tN - 1024) >> 7) + wn;
#pragma unroll
    for (int mi = 0; mi < 4; ++mi) {
      int key0 = ((int)tM + wm * 64 + mi * 16 + quad * 4) ^ 2048;
#pragma unroll
      for (int ni = 0; ni < 8; ++ni) {
        int d = ni * 16 + l16;
        f16x4 pk;
#pragma unroll
        for (int r = 0; r < 4; ++r) pk[r] = (f16)acc[mi][ni][r];
        *(f16x4*)&Vt[((long)kvh * 128 + d) * 4096 + key0] = pk;
      }
    }
  } else {
    // Q or K: in-register rope (partner pair = acc[mi][ni] / acc[mi][ni+4]).
    const float sc = isQ ? qscale : 1.0f;
    const int h = (int)(tN >> 7) + wn;  // Q: head 0..31; K: kv head 0..7
#pragma unroll
    for (int mi = 0; mi < 4; ++mi)
#pragma unroll
      for (int r = 0; r < 4; ++r) {
        int rg = (int)tM + wm * 64 + mi * 16 + quad * 4 + r;
        int pos = isQ ? (2048 + rg) : (rg ^ 2048);
        const float* cp = cosT + (long)pos * 128;
        const float* sp = sinT + (long)pos * 128;
        f16* orow = isQ ? Qb + ((long)h * 2048 + rg) * 128
                        : Kb + ((long)h * 4096 + pos) * 128;
#pragma unroll
        for (int ni = 0; ni < 4; ++ni) {
          int d = ni * 16 + l16;
          float x0 = acc[mi][ni][r], x1 = acc[mi][ni + 4][r];
          orow[d] = (f16)((x0 * cp[d] - x1 * sp[d]) * sc);
          orow[d + 64] = (f16)((x1 * cp[d + 64] + x0 * sp[d + 64]) * sc);
        }
      }
  }
#undef TILE_STEP
#undef STAGE_A
#undef STAGE_B
#undef LDA
#undef LDB
#undef WAITDS
#undef BAR
#undef MFMA16
}

// ---------------- flash attention (unchanged) ----------------
__global__ __launch_bounds__(256, 2) void flash_k(const f16* __restrict__ Qb,
                                                  const f16* __restrict__ Kb,
                                                  const f16* __restrict__ Vt,
                                                  f16* __restrict__ Ob) {
  __shared__ __align__(16) f16 Ks[64 * 128];    // [key][d], chunk c at slot c^(key&15)
  __shared__ __align__(16) f16 Vs[128 * 64];    // [d][key], chunk c at slot c^(d&7)
  __shared__ __align__(16) f16 Ps[4][32 * 72];  // per-wave P[q][key], stride 72
  const int tid = threadIdx.x;
  const int w = tid >> 6, lane = tid & 63;
  const int quad = lane >> 4, l16 = lane & 15;
  const int h = blockIdx.y;
  const int kvh = h >> 2;  // GQA
  const int q0 = blockIdx.x * 128;

  f16x8 qf[2][4];
#pragma unroll
  for (int mi = 0; mi < 2; ++mi) {
    const f16* qrow = Qb + ((long)h * 2048 + q0 + w * 32 + mi * 16 + l16) * 128 + quad * 8;
#pragma unroll
    for (int kc = 0; kc < 4; ++kc) qf[mi][kc] = *(const f16x8*)(qrow + kc * 32);
  }

  f32x4 of[2][8] = {};
  float lsum[2] = {0.f, 0.f};
  const f16* Kg = Kb + (long)kvh * 4096 * 128;
  const f16* Vg = Vt + (long)kvh * 128 * 4096;
  f16* PsW = &Ps[w][0];

  const int krow_in_wave = (lane >> 4);
  const int kslot = lane & 15;
  const int vrow_in_wave = (lane >> 3);
  const int vslot = lane & 7;
  const int vgc = vslot ^ (vrow_in_wave & 7);

  for (int kt = 0; kt < 64; ++kt) {
    __syncthreads();
#pragma unroll
    for (int it = 0; it < 4; ++it) {
      int row = w * 16 + it * 4 + krow_in_wave;
      int gc = kslot ^ (it * 4 + krow_in_wave);
      GLL16(Kg + (long)(kt * 64 + row) * 128 + gc * 8, &Ks[(w * 16 + it * 4) * 128]);
    }
#pragma unroll
    for (int it = 0; it < 4; ++it) {
      int row = w * 32 + it * 8 + vrow_in_wave;
      GLL16(Vg + (long)row * 4096 + kt * 64 + vgc * 8, &Vs[(w * 32 + it * 8) * 64]);
    }
    __syncthreads();
    f32x4 s[2][4] = {};
#pragma unroll
    for (int nt = 0; nt < 4; ++nt) {
      f16x8 ak[4];
#pragma unroll
      for (int kc = 0; kc < 4; ++kc) {
        int slot = (kc * 4 + quad) ^ l16;
        ak[kc] = *(const f16x8*)&Ks[(nt * 16 + l16) * 128 + slot * 8];
      }
#pragma unroll
      for (int mi = 0; mi < 2; ++mi)
#pragma unroll
        for (int kc = 0; kc < 4; ++kc)
          s[mi][nt] = __builtin_amdgcn_mfma_f32_16x16x32_f16(ak[kc], qf[mi][kc],
                                                             s[mi][nt], 0, 0, 0);
    }
#pragma unroll
    for (int mi = 0; mi < 2; ++mi)
#pragma unroll
      for (int nt = 0; nt < 4; ++nt) {
        f16x4 pk;
#pragma unroll
        for (int r = 0; r < 4; ++r) {
          float pv = __builtin_amdgcn_exp2f(s[mi][nt][r]);
          lsum[mi] += pv;
          pk[r] = (f16)pv;
        }
        *(f16x4*)&PsW[(mi * 16 + l16) * 72 + nt * 16 + quad * 4] = pk;
      }
#pragma unroll
    for (int kc2 = 0; kc2 < 2; ++kc2) {
      f16x8 bp[2];
#pragma unroll
      for (int mi = 0; mi < 2; ++mi)
        bp[mi] = *(const f16x8*)&PsW[(mi * 16 + l16) * 72 + kc2 * 32 + quad * 8];
#pragma unroll
      for (int dt = 0; dt < 8; ++dt) {
        int slot = (kc2 * 4 + quad) ^ (l16 & 7);
        f16x8 av = *(const f16x8*)&Vs[(dt * 16 + l16) * 64 + slot * 8];
#pragma unroll
        for (int mi = 0; mi < 2; ++mi)
          of[mi][dt] =
              __builtin_amdgcn_mfma_f32_16x16x32_f16(av, bp[mi], of[mi][dt], 0, 0, 0);
      }
    }
  }
#pragma unroll
  for (int mi = 0; mi < 2; ++mi) {
    float v = lsum[mi];
    v += __shfl_xor(v, 16, 64);
    v += __shfl_xor(v, 32, 64);
    float inv = 1.0f / v;
    long q = q0 + w * 32 + mi * 16 + l16;
#pragma unroll
    for (int dt = 0; dt < 8; ++dt) {
      f16x4 o4;
#pragma unroll
      for (int r = 0; r < 4; ++r) o4[r] = (f16)(of[mi][dt][r] * inv);
      *(f16x4*)&Ob[q * 4096 + h * 128 + dt * 16 + quad * 4] = o4;
    }
  }
}

__global__ void reduce2_k(const float* __restrict__ p, float* __restrict__ out) {
  long i = ((long)blockIdx.x * 256 + threadIdx.x) * 4;
  float4 a = *(const float4*)(p + i);
  float4 b = *(const float4*)(p + 8388608 + i);
  a.x += b.x; a.y += b.y; a.z += b.z; a.w += b.w;
  *(float4*)(out + i) = a;
}

// ---------------- host ----------------
extern "C" void kernel_launch(void* const* d_in, const int* in_sizes, int n_in,
                              void* d_out, int out_size, void* d_ws, size_t ws_size,
                              hipStream_t stream) {
  (void)in_sizes; (void)n_in; (void)out_size; (void)ws_size;
  const float* hidden = (const float*)d_in[0];
  const float* target = (const float*)d_in[1];
  const float* cosT = (const float*)d_in[2];
  const float* sinT = (const float*)d_in[3];
  const float* Wq = (const float*)d_in[4];
  const float* Wk = (const float*)d_in[5];
  const float* Wv = (const float*)d_in[6];
  const float* Wo = (const float*)d_in[7];
  float* out = (float*)d_out;

  char* p = (char*)d_ws;
  auto alloc = [&](size_t bytes) {
    char* r = p;
    p += (bytes + 255) & ~(size_t)255;
    return r;
  };
  f16* Xcat = (f16*)alloc(4096ull * 4096 * 2);    // rows 0..2047 hidden, 2048..4095 target
  f16* Wqb  = (f16*)alloc(4096ull * 4096 * 2);
  f16* Wkvb = (f16*)alloc(2048ull * 4096 * 2);    // rows 0..1023 Wk, 1024..2047 Wv
  f16* Wob  = (f16*)alloc(4096ull * 4096 * 2);
  f16* Qb   = (f16*)alloc(32ull * 2048 * 128 * 2);  // [h][q][d] (scaled)
  f16* Kb   = (f16*)alloc(8ull * 4096 * 128 * 2);   // [kvh][key][d]
  f16* Vt   = (f16*)alloc(8ull * 128 * 4096 * 2);   // [kvh][d][key]
  f16* Ao   = (f16*)alloc(2048ull * 4096 * 2);      // attn out (i, h*128+d)
  // split-K partials alias Xcat+Wqb (exactly 64 MiB, dead after flash_k)
  float* Pp = (float*)d_ws;

  cast_all_k<<<57344, 256, 0, stream>>>(hidden, target, Wq, Wk, Wv, Wo,
                                        Xcat, Wqb, Wkvb, Wob);

  const float QSC = (float)(0.08838834764831845 * 1.4426950408889634);
  gemm8k<0><<<256, 512, 0, stream>>>(Xcat, Wqb, Wkvb, cosT, sinT, Qb, Kb, Vt,
                                     nullptr, nullptr, nullptr, QSC);

  flash_k<<<dim3(16, 32), 256, 0, stream>>>(Qb, Kb, Vt, Ao);

  gemm8k<1><<<256, 512, 0, stream>>>(nullptr, nullptr, nullptr, nullptr, nullptr,
                                     nullptr, nullptr, nullptr, Ao, Wob, Pp, 0.f);
  reduce2_k<<<8192, 256, 0, stream>>>(Pp, out);
}

// Round 3
// 582.666 us; speedup vs baseline: 1.2066x; 1.0169x over previous
//
#include <hip/hip_runtime.h>

typedef unsigned short u16;
typedef _Float16 f16;
typedef _Float16 f16x4 __attribute__((ext_vector_type(4)));
typedef _Float16 f16x8 __attribute__((ext_vector_type(8)));
typedef float f32x4 __attribute__((ext_vector_type(4)));

#define GLL16(gptr, lptr)                                                        \
  __builtin_amdgcn_global_load_lds(                                              \
      (const __attribute__((address_space(1))) void*)(gptr),                     \
      (__attribute__((address_space(3))) void*)(lptr), 16, 0, 0)

// ---- cast all six fp32 inputs to fp16 in ONE dispatch (float4 units) ------
__global__ void cast_all_k(const float* __restrict__ h, const float* __restrict__ t,
                           const float* __restrict__ wq, const float* __restrict__ wk,
                           const float* __restrict__ wv, const float* __restrict__ wo,
                           f16* __restrict__ Xcat, f16* __restrict__ Wqb,
                           f16* __restrict__ Wkvb, f16* __restrict__ Wob) {
  long i = (long)blockIdx.x * 256 + threadIdx.x;
  const float* s; f16* d; long off;
  if (i < 2097152)        { s = h;  d = Xcat;            off = i; }
  else if (i < 4194304)   { s = t;  d = Xcat + 8388608;  off = i - 2097152; }
  else if (i < 8388608)   { s = wq; d = Wqb;             off = i - 4194304; }
  else if (i < 9437184)   { s = wk; d = Wkvb;            off = i - 8388608; }
  else if (i < 10485760)  { s = wv; d = Wkvb + 4194304;  off = i - 9437184; }
  else                    { s = wo; d = Wob;             off = i - 10485760; }
  float4 v = *(const float4*)(s + off * 4);
  f16x4 o;
  o.x = (f16)v.x; o.y = (f16)v.y; o.z = (f16)v.z; o.w = (f16)v.w;
  *(f16x4*)(d + off * 4) = o;
}

// ===========================================================================
// 256x256 8-phase GEMM-BT (BK=64) — unchanged (verified round 1).
// ===========================================================================
template <int MODE>
__global__ __launch_bounds__(512, 2) void gemm8k(
    const f16* __restrict__ Xcat, const f16* __restrict__ Wqb,
    const f16* __restrict__ Wkvb, const float* __restrict__ cosT,
    const float* __restrict__ sinT, f16* __restrict__ Qb, f16* __restrict__ Kb,
    f16* __restrict__ Vt, const f16* __restrict__ Ao,
    const f16* __restrict__ Wob, float* __restrict__ Cp, float qscale) {
  __shared__ __align__(16) f16 lds[65536];  // 128 KiB
  const int tid = threadIdx.x;
  const int w = tid >> 6, lane = tid & 63;
  const int quad = lane >> 4, l16 = lane & 15;
  const int wm = w >> 1, wn = w & 1;

  // T1: XCD-aware block swizzle (nwg=256, 256%8==0 -> bijective)
  int b = (int)blockIdx.x;
  int l = ((b & 7) << 5) | (b >> 3);

  const f16 *A, *B;
  long tM, tN;
  int NT, kbeg;
  bool isQ = false, isV = false;
  float* Cz = nullptr;
  if (MODE == 0) {
    kbeg = 0; NT = 64;
    if (l < 128) {  // Q: M=2048 (8 tiles) x N=4096 (16 tiles)
      A = Xcat; B = Wqb; tM = (long)(l >> 4) * 256; tN = (long)(l & 15) * 256;
      isQ = true;
    } else {        // KV: M=4096 (16) x N=2048 (8); cols>=1024 are V
      int l2 = l - 128;
      A = Xcat; B = Wkvb; tM = (long)(l2 >> 3) * 256; tN = (long)(l2 & 7) * 256;
      isV = (tN >= 1024);
    }
  } else {          // O-proj: M=2048 (8) x N=4096 (16), split-K z in {0,1}
    int z = l >> 7, r0 = l & 127;
    A = Ao; B = Wob; tM = (long)(r0 >> 4) * 256; tN = (long)(r0 & 15) * 256;
    kbeg = z * 2048; NT = 32; Cz = Cp + (long)z * 8388608;
  }

  const int sr8 = lane >> 3;
  const int cg = (lane & 7) ^ sr8;
  const f16* Ag = A + (tM + 16 * w + sr8) * 4096 + kbeg + cg * 8;
  const f16* Bg = B + (tN + 16 * w + sr8) * 4096 + kbeg + cg * 8;
  const int ldsw = w * 1024;

#define STAGE_A(hf, t, c)                                                      \
  do {                                                                         \
    const f16* g_ = Ag + (long)(t) * 64 + (long)(hf) * (128 * 4096);           \
    f16* d_ = &lds[(c) * 16384 + (hf) * 8192 + ldsw];                          \
    GLL16(g_, d_);                                                             \
    GLL16(g_ + 8 * 4096, d_ + 512);                                            \
  } while (0)
#define STAGE_B(hf, t, c)                                                      \
  do {                                                                         \
    const f16* g_ = Bg + (long)(t) * 64 + (long)(hf) * (128 * 4096);           \
    f16* d_ = &lds[32768 + (c) * 16384 + (hf) * 8192 + ldsw];                  \
    GLL16(g_, d_);                                                             \
    GLL16(g_ + 8 * 4096, d_ + 512);                                            \
  } while (0)

  const int rA = wm * 64 + l16;
  const int rB = wn * 128 + l16;
  const int sw = l16 & 7;
#define LDA(fr, mi, kk, c)                                                     \
  fr = *(const f16x8*)&lds[(c) * 16384 + (rA + (mi) * 16) * 64 +               \
                           (((kk) * 4 + quad) ^ sw) * 8]
#define LDB(fr, ni, kk, c)                                                     \
  fr = *(const f16x8*)&lds[32768 + (c) * 16384 + (rB + (ni) * 16) * 64 +       \
                           (((kk) * 4 + quad) ^ sw) * 8]

#define MFMA16 __builtin_amdgcn_mfma_f32_16x16x32_f16
#define BAR() __builtin_amdgcn_s_barrier()
#define WAITDS()                                                               \
  do {                                                                         \
    asm volatile("s_waitcnt lgkmcnt(0)" ::: "memory");                         \
    __builtin_amdgcn_sched_barrier(0);                                         \
  } while (0)

  f32x4 acc[4][8] = {};
  f16x8 af[2][2], bf0[4][2], bf1[4][2];

  STAGE_B(0, 0, 0); STAGE_B(1, 0, 0); STAGE_A(0, 0, 0); STAGE_A(1, 0, 0);
  STAGE_B(0, 1, 1); STAGE_B(1, 1, 1);
  asm volatile("s_waitcnt vmcnt(4)" ::: "memory");
  BAR();

#define TILE_STEP(t, c)                                                        \
  do {                                                                         \
    /* ---- phase 1: acc[0..1][0..3] ---- */                                   \
    LDA(af[0][0], 0, 0, c); LDA(af[0][1], 0, 1, c);                            \
    LDA(af[1][0], 1, 0, c); LDA(af[1][1], 1, 1, c);                            \
    LDB(bf0[0][0], 0, 0, c); LDB(bf0[0][1], 0, 1, c);                          \
    LDB(bf0[1][0], 1, 0, c); LDB(bf0[1][1], 1, 1, c);                          \
    LDB(bf0[2][0], 2, 0, c); LDB(bf0[2][1], 2, 1, c);                          \
    LDB(bf0[3][0], 3, 0, c); LDB(bf0[3][1], 3, 1, c);                          \
    if ((t) + 1 < NT) STAGE_A(0, (t) + 1, (c) ^ 1);                            \
    BAR(); WAITDS();                                                           \
    __builtin_amdgcn_s_setprio(1);                                             \
    _Pragma("unroll") for (int mi = 0; mi < 2; ++mi)                           \
        _Pragma("unroll") for (int ni = 0; ni < 4; ++ni) {                     \
      acc[mi][ni] = MFMA16(af[mi][0], bf0[ni][0], acc[mi][ni], 0, 0, 0);       \
      acc[mi][ni] = MFMA16(af[mi][1], bf0[ni][1], acc[mi][ni], 0, 0, 0);       \
    }                                                                          \
    __builtin_amdgcn_s_setprio(0);                                             \
    BAR();                                                                     \
    /* ---- phase 2: acc[0..1][4..7] ---- */                                   \
    LDB(bf1[0][0], 4, 0, c); LDB(bf1[0][1], 4, 1, c);                          \
    LDB(bf1[1][0], 5, 0, c); LDB(bf1[1][1], 5, 1, c);                          \
    LDB(bf1[2][0], 6, 0, c); LDB(bf1[2][1], 6, 1, c);                          \
    LDB(bf1[3][0], 7, 0, c); LDB(bf1[3][1], 7, 1, c);                          \
    if ((t) + 1 < NT) STAGE_A(1, (t) + 1, (c) ^ 1);                            \
    BAR(); WAITDS();                                                           \
    __builtin_amdgcn_s_setprio(1);                                             \
    _Pragma("unroll") for (int mi = 0; mi < 2; ++mi)                           \
        _Pragma("unroll") for (int ni = 0; ni < 4; ++ni) {                     \
      acc[mi][4 + ni] =                                                        \
          MFMA16(af[mi][0], bf1[ni][0], acc[mi][4 + ni], 0, 0, 0);             \
      acc[mi][4 + ni] =                                                        \
          MFMA16(af[mi][1], bf1[ni][1], acc[mi][4 + ni], 0, 0, 0);             \
    }                                                                          \
    __builtin_amdgcn_s_setprio(0);                                             \
    BAR();                                                                     \
    /* ---- phase 3: acc[2..3][0..3] ---- */                                   \
    LDA(af[0][0], 2, 0, c); LDA(af[0][1], 2, 1, c);                            \
    LDA(af[1][0], 3, 0, c); LDA(af[1][1], 3, 1, c);                            \
    if ((t) + 2 < NT) STAGE_B(0, (t) + 2, c);                                  \
    BAR(); WAITDS();                                                           \
    __builtin_amdgcn_s_setprio(1);                                             \
    _Pragma("unroll") for (int mi = 0; mi < 2; ++mi)                           \
        _Pragma("unroll") for (int ni = 0; ni < 4; ++ni) {                     \
      acc[2 + mi][ni] = MFMA16(af[mi][0], bf0[ni][0], acc[2 + mi][ni], 0, 0, 0);\
      acc[2 + mi][ni] = MFMA16(af[mi][1], bf0[ni][1], acc[2 + mi][ni], 0, 0, 0);\
    }                                                                          \
    __builtin_amdgcn_s_setprio(0);                                             \
    BAR();                                                                     \
    /* ---- phase 4: acc[2..3][4..7], single counted vmcnt per K-tile ---- */  \
    if ((t) + 2 < NT) STAGE_B(1, (t) + 2, c);                                  \
    BAR();                                                                     \
    __builtin_amdgcn_s_setprio(1);                                             \
    _Pragma("unroll") for (int mi = 0; mi < 2; ++mi)                           \
        _Pragma("unroll") for (int ni = 0; ni < 4; ++ni) {                     \
      acc[2 + mi][4 + ni] =                                                    \
          MFMA16(af[mi][0], bf1[ni][0], acc[2 + mi][4 + ni], 0, 0, 0);         \
      acc[2 + mi][4 + ni] =                                                    \
          MFMA16(af[mi][1], bf1[ni][1], acc[2 + mi][4 + ni], 0, 0, 0);         \
    }                                                                          \
    __builtin_amdgcn_s_setprio(0);                                             \
    if ((t) + 2 < NT)                                                          \
      asm volatile("s_waitcnt vmcnt(4)" ::: "memory");                         \
    else                                                                       \
      asm volatile("s_waitcnt vmcnt(0)" ::: "memory");                         \
    BAR();                                                                     \
  } while (0)

  for (int t = 0; t < NT; t += 2) {
    TILE_STEP(t, 0);
    TILE_STEP(t + 1, 1);
  }

  // ------------------------------ epilogues --------------------------------
  if (MODE == 1) {
#pragma unroll
    for (int mi = 0; mi < 4; ++mi)
#pragma unroll
      for (int ni = 0; ni < 8; ++ni)
#pragma unroll
        for (int r = 0; r < 4; ++r) {
          long row = tM + wm * 64 + mi * 16 + quad * 4 + r;
          long col = tN + wn * 128 + ni * 16 + l16;
          Cz[row * 4096 + col] = acc[mi][ni][r];
        }
  } else if (isV) {
    const int kvh = (int)((tN - 1024) >> 7) + wn;
#pragma unroll
    for (int mi = 0; mi < 4; ++mi) {
      int key0 = ((int)tM + wm * 64 + mi * 16 + quad * 4) ^ 2048;
#pragma unroll
      for (int ni = 0; ni < 8; ++ni) {
        int d = ni * 16 + l16;
        f16x4 pk;
#pragma unroll
        for (int r = 0; r < 4; ++r) pk[r] = (f16)acc[mi][ni][r];
        *(f16x4*)&Vt[((long)kvh * 128 + d) * 4096 + key0] = pk;
      }
    }
  } else {
    const float sc = isQ ? qscale : 1.0f;
    const int h = (int)(tN >> 7) + wn;
#pragma unroll
    for (int mi = 0; mi < 4; ++mi)
#pragma unroll
      for (int r = 0; r < 4; ++r) {
        int rg = (int)tM + wm * 64 + mi * 16 + quad * 4 + r;
        int pos = isQ ? (2048 + rg) : (rg ^ 2048);
        const float* cp = cosT + (long)pos * 128;
        const float* sp = sinT + (long)pos * 128;
        f16* orow = isQ ? Qb + ((long)h * 2048 + rg) * 128
                        : Kb + ((long)h * 4096 + pos) * 128;
#pragma unroll
        for (int ni = 0; ni < 4; ++ni) {
          int d = ni * 16 + l16;
          float x0 = acc[mi][ni][r], x1 = acc[mi][ni + 4][r];
          orow[d] = (f16)((x0 * cp[d] - x1 * sp[d]) * sc);
          orow[d + 64] = (f16)((x1 * cp[d + 64] + x0 * sp[d + 64]) * sc);
        }
      }
  }
#undef TILE_STEP
#undef STAGE_A
#undef STAGE_B
#undef LDA
#undef LDB
#undef WAITDS
#undef BAR
#undef MFMA16
}

// ===========================================================================
// flash attention — counted-vmcnt pipeline (T3/T4) + kvh->XCD swizzle (T1) +
// setprio (T5).  K double-buffered; V staged at iter top (overlaps QK^T);
// K(t+1) staged after QK^T (overlaps exp+PV).  Raw s_barrier (NO vmcnt(0)
// drain) + explicit counted waits:
//   per iter kt (c=kt&1):
//     BAR          // Vs reads (kt-1) + Ks[c^1] reads (kt-1) done, all waves
//     issue 4x V(kt)                 -> in flight: K(kt)[4 oldest] + V(kt)[4]
//     vmcnt(4)     // K(kt) landed (mine); V still flying
//     BAR + schedbar                 // K(kt) landed for ALL waves
//     QK^T (32 MFMA, setprio)
//     issue 4x K(kt+1) -> Ks[c^1]    // overwrite safe: last read kt-1 < BAR
//     exp + P pack/store (VALU)      // K loads fly under this
//     vmcnt(4) [kt<63] / vmcnt(0)    // V(kt) landed (K(kt+1) are the 4 newest)
//     BAR + schedbar                 // V landed for ALL waves
//     PV (32 MFMA, setprio)
// LDS: Ks dbuf 32K + Vs 16K + Ps 18.4K = 66K -> 2 blocks/CU (unchanged).
// Grid 512 linear, kvh = b&7: all 64 blocks of one kv head land on one XCD
// (b%8 round-robin) -> K+V (2 MB) fits that XCD's 4 MB L2.
// ===========================================================================
__global__ __launch_bounds__(256, 2) void flash_k(const f16* __restrict__ Qb,
                                                  const f16* __restrict__ Kb,
                                                  const f16* __restrict__ Vt,
                                                  f16* __restrict__ Ob) {
  __shared__ __align__(16) f16 Ks[2][64 * 128];  // [key][d], chunk cc at slot cc^(key&15)
  __shared__ __align__(16) f16 Vs[128 * 64];     // [d][key], chunk cc at slot cc^(d&7)
  __shared__ __align__(16) f16 Ps[4][32 * 72];   // per-wave P[q][key], stride 72
  const int tid = threadIdx.x;
  const int w = tid >> 6, lane = tid & 63;
  const int quad = lane >> 4, l16 = lane & 15;
  const int b = blockIdx.x;          // 512 blocks
  const int kvh = b & 7;             // -> XCD b%8
  const int j = b >> 3;              // 0..63
  const int h = kvh * 4 + (j >> 4);  // q head
  const int q0 = (j & 15) * 128;

  f16x8 qf[2][4];
#pragma unroll
  for (int mi = 0; mi < 2; ++mi) {
    const f16* qrow = Qb + ((long)h * 2048 + q0 + w * 32 + mi * 16 + l16) * 128 + quad * 8;
#pragma unroll
    for (int kc = 0; kc < 4; ++kc) qf[mi][kc] = *(const f16x8*)(qrow + kc * 32);
  }

  f32x4 of[2][8] = {};
  float lsum[2] = {0.f, 0.f};
  const f16* Kg = Kb + (long)kvh * 4096 * 128;
  const f16* Vg = Vt + (long)kvh * 128 * 4096;
  f16* PsW = &Ps[w][0];

  const int krow = (lane >> 4);
  const int kslot = lane & 15;
  const int vrow = (lane >> 3);
  const int vslot = lane & 7;
  const int vgc = vslot ^ (vrow & 7);

#define FBAR() __builtin_amdgcn_s_barrier()
#define STAGE_K(kt_, c_)                                                       \
  do {                                                                         \
    _Pragma("unroll") for (int it = 0; it < 4; ++it) {                         \
      int row = w * 16 + it * 4 + krow;                                        \
      int gc = kslot ^ (it * 4 + krow);                                        \
      GLL16(Kg + (long)((kt_)*64 + row) * 128 + gc * 8,                        \
            &Ks[c_][(w * 16 + it * 4) * 128]);                                 \
    }                                                                          \
  } while (0)
#define STAGE_V(kt_)                                                           \
  do {                                                                         \
    _Pragma("unroll") for (int it = 0; it < 4; ++it) {                         \
      int row = w * 32 + it * 8 + vrow;                                        \
      GLL16(Vg + (long)row * 4096 + (kt_)*64 + vgc * 8,                        \
            &Vs[(w * 32 + it * 8) * 64]);                                      \
    }                                                                          \
  } while (0)

  STAGE_K(0, 0);  // prologue: K(0) in flight

  for (int kt = 0; kt < 64; ++kt) {
    const int c = kt & 1;
    FBAR();                                   // Vs + Ks[c^1] free
    STAGE_V(kt);
    asm volatile("s_waitcnt vmcnt(4)" ::: "memory");  // K(kt) landed
    FBAR();
    __builtin_amdgcn_sched_barrier(0);

    // ---- QK^T from Ks[c] ----
    f32x4 s[2][4] = {};
    __builtin_amdgcn_s_setprio(1);
#pragma unroll
    for (int nt = 0; nt < 4; ++nt) {
      f16x8 ak[4];
#pragma unroll
      for (int kc = 0; kc < 4; ++kc) {
        int slot = (kc * 4 + quad) ^ l16;
        ak[kc] = *(const f16x8*)&Ks[c][(nt * 16 + l16) * 128 + slot * 8];
      }
#pragma unroll
      for (int mi = 0; mi < 2; ++mi)
#pragma unroll
        for (int kc = 0; kc < 4; ++kc)
          s[mi][nt] = __builtin_amdgcn_mfma_f32_16x16x32_f16(ak[kc], qf[mi][kc],
                                                             s[mi][nt], 0, 0, 0);
    }
    __builtin_amdgcn_s_setprio(0);

    if (kt < 63) STAGE_K(kt + 1, c ^ 1);      // flies under exp + PV

    // ---- exp + P pack (VALU) ----
#pragma unroll
    for (int mi = 0; mi < 2; ++mi)
#pragma unroll
      for (int nt = 0; nt < 4; ++nt) {
        f16x4 pk;
#pragma unroll
        for (int r = 0; r < 4; ++r) {
          float pv = __builtin_amdgcn_exp2f(s[mi][nt][r]);
          lsum[mi] += pv;
          pk[r] = (f16)pv;
        }
        *(f16x4*)&PsW[(mi * 16 + l16) * 72 + nt * 16 + quad * 4] = pk;
      }

    if (kt < 63)
      asm volatile("s_waitcnt vmcnt(4)" ::: "memory");  // V(kt) landed
    else
      asm volatile("s_waitcnt vmcnt(0)" ::: "memory");
    FBAR();
    __builtin_amdgcn_sched_barrier(0);

    // ---- PV from Vs ----
    __builtin_amdgcn_s_setprio(1);
#pragma unroll
    for (int kc2 = 0; kc2 < 2; ++kc2) {
      f16x8 bp[2];
#pragma unroll
      for (int mi = 0; mi < 2; ++mi)
        bp[mi] = *(const f16x8*)&PsW[(mi * 16 + l16) * 72 + kc2 * 32 + quad * 8];
#pragma unroll
      for (int dt = 0; dt < 8; ++dt) {
        int slot = (kc2 * 4 + quad) ^ (l16 & 7);
        f16x8 av = *(const f16x8*)&Vs[(dt * 16 + l16) * 64 + slot * 8];
#pragma unroll
        for (int mi = 0; mi < 2; ++mi)
          of[mi][dt] =
              __builtin_amdgcn_mfma_f32_16x16x32_f16(av, bp[mi], of[mi][dt], 0, 0, 0);
      }
    }
    __builtin_amdgcn_s_setprio(0);
  }
#undef STAGE_K
#undef STAGE_V
#undef FBAR

#pragma unroll
  for (int mi = 0; mi < 2; ++mi) {
    float v = lsum[mi];
    v += __shfl_xor(v, 16, 64);
    v += __shfl_xor(v, 32, 64);
    float inv = 1.0f / v;
    long q = q0 + w * 32 + mi * 16 + l16;
#pragma unroll
    for (int dt = 0; dt < 8; ++dt) {
      f16x4 o4;
#pragma unroll
      for (int r = 0; r < 4; ++r) o4[r] = (f16)(of[mi][dt][r] * inv);
      *(f16x4*)&Ob[q * 4096 + h * 128 + dt * 16 + quad * 4] = o4;
    }
  }
}

__global__ void reduce2_k(const float* __restrict__ p, float* __restrict__ out) {
  long i = ((long)blockIdx.x * 256 + threadIdx.x) * 4;
  float4 a = *(const float4*)(p + i);
  float4 b = *(const float4*)(p + 8388608 + i);
  a.x += b.x; a.y += b.y; a.z += b.z; a.w += b.w;
  *(float4*)(out + i) = a;
}

// ---------------- host ----------------
extern "C" void kernel_launch(void* const* d_in, const int* in_sizes, int n_in,
                              void* d_out, int out_size, void* d_ws, size_t ws_size,
                              hipStream_t stream) {
  (void)in_sizes; (void)n_in; (void)out_size; (void)ws_size;
  const float* hidden = (const float*)d_in[0];
  const float* target = (const float*)d_in[1];
  const float* cosT = (const float*)d_in[2];
  const float* sinT = (const float*)d_in[3];
  const float* Wq = (const float*)d_in[4];
  const float* Wk = (const float*)d_in[5];
  const float* Wv = (const float*)d_in[6];
  const float* Wo = (const float*)d_in[7];
  float* out = (float*)d_out;

  char* p = (char*)d_ws;
  auto alloc = [&](size_t bytes) {
    char* r = p;
    p += (bytes + 255) & ~(size_t)255;
    return r;
  };
  f16* Xcat = (f16*)alloc(4096ull * 4096 * 2);    // rows 0..2047 hidden, 2048..4095 target
  f16* Wqb  = (f16*)alloc(4096ull * 4096 * 2);
  f16* Wkvb = (f16*)alloc(2048ull * 4096 * 2);    // rows 0..1023 Wk, 1024..2047 Wv
  f16* Wob  = (f16*)alloc(4096ull * 4096 * 2);
  f16* Qb   = (f16*)alloc(32ull * 2048 * 128 * 2);  // [h][q][d] (scaled)
  f16* Kb   = (f16*)alloc(8ull * 4096 * 128 * 2);   // [kvh][key][d]
  f16* Vt   = (f16*)alloc(8ull * 128 * 4096 * 2);   // [kvh][d][key]
  f16* Ao   = (f16*)alloc(2048ull * 4096 * 2);      // attn out (i, h*128+d)
  // split-K partials alias Xcat+Wqb (exactly 64 MiB, dead after flash_k)
  float* Pp = (float*)d_ws;

  cast_all_k<<<57344, 256, 0, stream>>>(hidden, target, Wq, Wk, Wv, Wo,
                                        Xcat, Wqb, Wkvb, Wob);

  const float QSC = (float)(0.08838834764831845 * 1.4426950408889634);
  gemm8k<0><<<256, 512, 0, stream>>>(Xcat, Wqb, Wkvb, cosT, sinT, Qb, Kb, Vt,
                                     nullptr, nullptr, nullptr, QSC);

  flash_k<<<512, 256, 0, stream>>>(Qb, Kb, Vt, Ao);

  gemm8k<1><<<256, 512, 0, stream>>>(nullptr, nullptr, nullptr, nullptr, nullptr,
                                     nullptr, nullptr, nullptr, Ao, Wob, Pp, 0.f);
  reduce2_k<<<8192, 256, 0, stream>>>(Pp, out);
}